// Round 2
// baseline (682.251 us; speedup 1.0000x reference)
//
#include <hip/hip_runtime.h>
#include <hip/hip_bf16.h>

#define DD 256
#define ROWS 64

typedef __attribute__((ext_vector_type(8))) short bf16x8;
typedef __attribute__((ext_vector_type(4))) float f32x4;

__device__ __forceinline__ ushort f2bf(float f) {
    unsigned u = __float_as_uint(f);
    u += 0x7fffu + ((u >> 16) & 1u);
    return (ushort)(u >> 16);
}

__device__ __forceinline__ float mish_f(float t) {
    // mish(t) = t * tanh(softplus(t)) = t * (u^2+2u)/(u^2+2u+2), u = e^t
    float u = __expf(t);
    float w = u * (u + 2.0f);
    float r = t * (w / (w + 2.0f));
    return (t > 15.0f) ? t : r;   // avoid u^2 overflow; tanh(softplus(15)) == 1 in fp32
}

// Stage up to 64 rows x 256 cols of fp32 into bf16 LDS, XOR-swizzled.
// lds layout: row*512 bytes + (kbyte ^ ((row&7)<<4))
// Tile = 64*256/4 = 4096 float4 chunks; 256 threads => 16 iterations.
__device__ __forceinline__ void stage_rows(const float* __restrict__ src,
                                           int rowsValid, char* lds) {
    const int t = threadIdx.x;
#pragma unroll
    for (int i = 0; i < 16; ++i) {
        int c = i * 256 + t;           // 16B-source chunk id, 0..4095
        int row = c >> 6;              // 0..63
        int col4 = (c & 63) << 2;      // col start, multiple of 4
        float4 v = make_float4(0.f, 0.f, 0.f, 0.f);
        if (row < rowsValid)
            v = *(const float4*)(src + (size_t)row * DD + col4);
        ushort4 h;
        h.x = f2bf(v.x); h.y = f2bf(v.y); h.z = f2bf(v.z); h.w = f2bf(v.w);
        int off = row * 512 + ((col4 * 2) ^ ((row & 7) << 4));
        *(ushort4*)(lds + off) = h;
    }
}

// 64x256 @ 256x256^T: each of 4 waves computes 16 rows x 256 cols.
// A-frag: row=lane&15, k=(lane>>4)*8.. ; B-frag: col=lane&15, same k (B[k][j]=W[j][k]).
__device__ __forceinline__ void gemm_core(const char* lds, const ushort* __restrict__ Wbf,
                                          f32x4 acc[16]) {
    const int lane = threadIdx.x & 63;
    const int wave = threadIdx.x >> 6;
    const int r = lane & 15;
    const int halfk = lane >> 4;
    const int row = wave * 16 + r;
    bf16x8 afr[8];
#pragma unroll
    for (int ks = 0; ks < 8; ++ks) {
        int kbyte = ks * 64 + halfk * 16;
        afr[ks] = *(const bf16x8*)(lds + row * 512 + (kbyte ^ ((row & 7) << 4)));
    }
#pragma unroll
    for (int ct = 0; ct < 16; ++ct) {
        const ushort* wrow = Wbf + (size_t)(ct * 16 + r) * DD + halfk * 8;
#pragma unroll
        for (int ks = 0; ks < 8; ++ks) {
            bf16x8 bfr = *(const bf16x8*)(wrow + ks * 32);
            acc[ct] = __builtin_amdgcn_mfma_f32_16x16x32_bf16(afr[ks], bfr, acc[ct], 0, 0, 0);
        }
    }
}

__global__ void __launch_bounds__(256) convert_w_kernel(const float* __restrict__ in,
                                                        ushort* __restrict__ out, int n4) {
    int i = blockIdx.x * blockDim.x + threadIdx.x;
    if (i < n4) {
        float4 v = ((const float4*)in)[i];
        ushort4 h;
        h.x = f2bf(v.x); h.y = f2bf(v.y); h.z = f2bf(v.z); h.w = f2bf(v.w);
        ((ushort4*)out)[i] = h;
    }
}

// x = mish(node @ Wd^T + bd); write to x (ws) and agg (d_out, as the "+ x" term of rst)
__global__ void __launch_bounds__(256) node_kernel(const float* __restrict__ nf,
                                                   const ushort* __restrict__ Wd,
                                                   const float* __restrict__ bd,
                                                   float* __restrict__ x,
                                                   float* __restrict__ agg, int M) {
    __shared__ char lds[ROWS * 512];
    const int base = blockIdx.x * ROWS;
    const int rowsValid = min(ROWS, M - base);
    stage_rows(nf + (size_t)base * DD, rowsValid, lds);
    __syncthreads();
    f32x4 acc[16];
#pragma unroll
    for (int i = 0; i < 16; ++i) acc[i] = (f32x4){0.f, 0.f, 0.f, 0.f};
    gemm_core(lds, Wd, acc);
    const int lane = threadIdx.x & 63;
    const int wave = threadIdx.x >> 6;
    const int r = lane & 15, q = lane >> 4;
#pragma unroll
    for (int ct = 0; ct < 16; ++ct) {
        int col = ct * 16 + r;
        float bb = bd[col];
#pragma unroll
        for (int j = 0; j < 4; ++j) {
            int lrow = wave * 16 + q * 4 + j;
            if (lrow < rowsValid) {
                size_t idx = (size_t)(base + lrow) * DD + col;
                float m = mish_f(acc[ct][j] + bb);
                x[idx] = m;
                agg[idx] = m;
            }
        }
    }
}

// y = mish(edge @ We^T + be); msg = relu(x[src] + y); atomicAdd into agg[dst]
__global__ void __launch_bounds__(256) edge_kernel(const float* __restrict__ ef,
                                                   const ushort* __restrict__ We,
                                                   const float* __restrict__ be,
                                                   const float* __restrict__ x,
                                                   const int* __restrict__ src,
                                                   const int* __restrict__ dst,
                                                   float* __restrict__ agg, int E) {
    __shared__ char lds[ROWS * 512];
    const int base = blockIdx.x * ROWS;
    const int rowsValid = min(ROWS, E - base);
    stage_rows(ef + (size_t)base * DD, rowsValid, lds);
    __syncthreads();
    f32x4 acc[16];
#pragma unroll
    for (int i = 0; i < 16; ++i) acc[i] = (f32x4){0.f, 0.f, 0.f, 0.f};
    gemm_core(lds, We, acc);
    const int lane = threadIdx.x & 63;
    const int wave = threadIdx.x >> 6;
    const int r = lane & 15, q = lane >> 4;
    int s4[4], d4[4];
#pragma unroll
    for (int j = 0; j < 4; ++j) {
        int lrow = wave * 16 + q * 4 + j;
        int grow = base + ((lrow < rowsValid) ? lrow : 0);
        s4[j] = src[grow];
        d4[j] = dst[grow];
    }
#pragma unroll
    for (int ct = 0; ct < 16; ++ct) {
        int col = ct * 16 + r;
        float bb = be[col];
#pragma unroll
        for (int j = 0; j < 4; ++j) {
            int lrow = wave * 16 + q * 4 + j;
            if (lrow < rowsValid) {
                float y = mish_f(acc[ct][j] + bb);
                float xv = x[(size_t)s4[j] * DD + col];
                float msg = fmaxf(xv + y, 0.f);
                atomicAdd(agg + (size_t)d4[j] * DD + col, msg);
            }
        }
    }
}

// out = mish(agg @ Wo^T + bo), in place on agg (= d_out)
__global__ void __launch_bounds__(256) out_kernel(const ushort* __restrict__ Wo,
                                                  const float* __restrict__ bo,
                                                  float* __restrict__ agg_out, int M) {
    __shared__ char lds[ROWS * 512];
    const int base = blockIdx.x * ROWS;
    const int rowsValid = min(ROWS, M - base);
    stage_rows(agg_out + (size_t)base * DD, rowsValid, lds);
    __syncthreads();
    f32x4 acc[16];
#pragma unroll
    for (int i = 0; i < 16; ++i) acc[i] = (f32x4){0.f, 0.f, 0.f, 0.f};
    gemm_core(lds, Wo, acc);
    const int lane = threadIdx.x & 63;
    const int wave = threadIdx.x >> 6;
    const int r = lane & 15, q = lane >> 4;
#pragma unroll
    for (int ct = 0; ct < 16; ++ct) {
        int col = ct * 16 + r;
        float bb = bo[col];
#pragma unroll
        for (int j = 0; j < 4; ++j) {
            int lrow = wave * 16 + q * 4 + j;
            if (lrow < rowsValid) {
                size_t idx = (size_t)(base + lrow) * DD + col;
                agg_out[idx] = mish_f(acc[ct][j] + bb);
            }
        }
    }
}

extern "C" void kernel_launch(void* const* d_in, const int* in_sizes, int n_in,
                              void* d_out, int out_size, void* d_ws, size_t ws_size,
                              hipStream_t stream) {
    const float* nf = (const float*)d_in[0];
    const float* ef = (const float*)d_in[1];
    // d_in[2] = targets: unused by the reference output
    const int* src = (const int*)d_in[3];
    const int* dst = (const int*)d_in[4];
    const float* Wd = (const float*)d_in[5];
    const float* bd = (const float*)d_in[6];
    const float* We = (const float*)d_in[7];
    const float* be = (const float*)d_in[8];
    const float* Wo = (const float*)d_in[9];
    const float* bo = (const float*)d_in[10];

    const int M = in_sizes[0] / DD;   // 20000
    const int E = in_sizes[1] / DD;   // 320000
    float* out = (float*)d_out;       // doubles as agg: rst = x + sum(msg)

    char* ws = (char*)d_ws;
    float* x = (float*)ws;                          // M*256 fp32
    size_t xbytes = ((size_t)M * DD * sizeof(float) + 255) & ~(size_t)255;
    ushort* Wdb = (ushort*)(ws + xbytes);           // 3 x 64K bf16 weights
    ushort* Web = Wdb + DD * DD;
    ushort* Wob = Web + DD * DD;

    const int n4 = DD * DD / 4;  // 16384 float4 chunks per weight
    convert_w_kernel<<<(n4 + 255) / 256, 256, 0, stream>>>(Wd, Wdb, n4);
    convert_w_kernel<<<(n4 + 255) / 256, 256, 0, stream>>>(We, Web, n4);
    convert_w_kernel<<<(n4 + 255) / 256, 256, 0, stream>>>(Wo, Wob, n4);

    const int nwgN = (M + ROWS - 1) / ROWS;
    node_kernel<<<nwgN, 256, 0, stream>>>(nf, Wdb, bd, x, out, M);
    const int nwgE = (E + ROWS - 1) / ROWS;
    edge_kernel<<<nwgE, 256, 0, stream>>>(ef, Web, be, x, src, dst, out, E);
    out_kernel<<<nwgN, 256, 0, stream>>>(Wob, bo, out, M);
}